// Round 7
// baseline (2405.822 us; speedup 1.0000x reference)
//
#include <hip/hip_runtime.h>

#define N_NODES 100000
#define N_EDGES 1600000

#define BNODES 32
#define NBUCK 3125          // 100000 / 32 exactly
#define NSUB 8              // one sub-bucket per XCD (blockIdx & 7)
#define SUBCAP 128          // mean 64, ~8 sigma headroom

typedef unsigned int uint;
typedef unsigned short u16;
typedef __attribute__((ext_vector_type(8))) short bf16x8;  // 8 bf16 (4 VGPRs)
typedef __attribute__((ext_vector_type(4))) float f32x4;

__device__ __forceinline__ uint bf16_rtne(float f) {
  uint u = __float_as_uint(f);
  return (u + 0x7fffu + ((u >> 16) & 1u)) >> 16;
}

// ---------------- bucketed edge staging ----------------

__global__ __launch_bounds__(256) void k_zero_cur(int* __restrict__ bcur) {
  int i = blockIdx.x * 256 + threadIdx.x;
  if (i < NBUCK * NSUB) bcur[i] = 0;
}

// Append edges into dst-buckets; sub-bucket = blockIdx&7 keeps each stage
// region + cursor owned by ONE XCD's L2 (round-robin dispatch) -> ~1x write amp.
__global__ __launch_bounds__(256) void k_bucket(const int* __restrict__ ei, int* __restrict__ bcur,
                                                uint* __restrict__ stage) {
  int e = blockIdx.x * 256 + threadIdx.x;
  int sub = blockIdx.x & (NSUB - 1);
  if (e < N_EDGES) {
    int s = ei[e];
    int d = ei[N_EDGES + e];
    int b = d >> 5;
    int idx = sub * NBUCK + b;
    int pos = atomicAdd(&bcur[idx], 1);
    if (pos < SUBCAP)  // overflow guard (statistically unreachable)
      stage[idx * SUBCAP + pos] = (uint)s | ((uint)(d & 31) << 17);
  }
}

// per-bucket degree count (LDS only) -> dinv
__global__ __launch_bounds__(256) void k_bcount(const int* __restrict__ bcur, const uint* __restrict__ stage,
                                                float* __restrict__ dinv) {
  __shared__ int cnt[BNODES];
  int b = blockIdx.x, t = threadIdx.x;
  if (t < BNODES) cnt[t] = 0;
  __syncthreads();
  for (int s = 0; s < NSUB; ++s) {
    int idx = s * NBUCK + b;
    int n = bcur[idx]; if (n > SUBCAP) n = SUBCAP;
    int base = idx * SUBCAP;
    for (int i = t; i < n; i += 256) atomicAdd(&cnt[stage[base + i] >> 17], 1);
  }
  __syncthreads();
  if (t < BNODES) dinv[b * BNODES + t] = rsqrtf((float)(cnt[t] + 1));  // +1 self-loop
}

// ---------------- W pre-swizzle to MFMA B-fragment order ----------------
// unit u = (nt*4+kc)*64 + lane ; element j = W[kc*32+(lane>>4)*8+j][nt*16+(lane&15)]

__global__ __launch_bounds__(256) void k_prepw(const float* __restrict__ W1, const float* __restrict__ W2,
                                               uint* __restrict__ S1, uint* __restrict__ S2) {
  int u = blockIdx.x * 256 + threadIdx.x;  // 0..2047
  const float* W = blockIdx.y ? W2 : W1;
  uint* S = blockIdx.y ? S2 : S1;
  int lane = u & 63;
  int kcnt = u >> 6;
  int kc = kcnt & 3;
  int nt = kcnt >> 2;
  int n = nt * 16 + (lane & 15);
  int k0 = kc * 32 + (lane >> 4) * 8;
  float f[8];
#pragma unroll
  for (int j = 0; j < 8; ++j) f[j] = W[(size_t)(k0 + j) * 128 + n];
  uint4 pk;
  pk.x = bf16_rtne(f[0]) | (bf16_rtne(f[1]) << 16);
  pk.y = bf16_rtne(f[2]) | (bf16_rtne(f[3]) << 16);
  pk.z = bf16_rtne(f[4]) | (bf16_rtne(f[5]) << 16);
  pk.w = bf16_rtne(f[6]) | (bf16_rtne(f[7]) << 16);
  ((uint4*)S)[u] = pk;
}

// ---------------- MFMA GEMM: OutH[nrows,128](bf16) = A[nrows,128] @ W ----------------
// 64 rows/block, 4 waves, wave w owns rows w*16..w*16+15, sweeps 8 n-tiles.

__global__ __launch_bounds__(256) void k_gemm(const void* __restrict__ Ain, int a_f32,
                                              const uint* __restrict__ Wsw,
                                              u16* __restrict__ OutH, int nrows) {
  __shared__ uint As[4096];   // 16 KB A fragments
  __shared__ uint Bs[8192];   // 32 KB B fragments
  const int tid = threadIdx.x;
  const int R = blockIdx.x * 64;
  {
    const uint4* src = (const uint4*)Wsw;
    uint4* dst = (uint4*)Bs;
#pragma unroll
    for (int v = 0; v < 8; ++v) dst[tid + v * 256] = src[tid + v * 256];
  }
  const int unit = tid & 15;      // k8-slice 0..15
  const int kc_s = unit >> 2;
  const int quad_s = unit & 3;
#pragma unroll
  for (int pass = 0; pass < 4; ++pass) {
    int row = pass * 16 + (tid >> 4);
    int gr = R + row;
    if (gr >= nrows) gr = nrows - 1;
    uint4 pk;
    if (a_f32) {
      const float* srcr = (const float*)Ain + (size_t)gr * 128 + unit * 8;
      float4 f0 = ((const float4*)srcr)[0];
      float4 f1 = ((const float4*)srcr)[1];
      pk.x = bf16_rtne(f0.x) | (bf16_rtne(f0.y) << 16);
      pk.y = bf16_rtne(f0.z) | (bf16_rtne(f0.w) << 16);
      pk.z = bf16_rtne(f1.x) | (bf16_rtne(f1.y) << 16);
      pk.w = bf16_rtne(f1.z) | (bf16_rtne(f1.w) << 16);
    } else {
      pk = ((const uint4*)((const uint*)Ain + (size_t)gr * 64))[unit];
    }
    int wv = row >> 4;
    int lane_t = quad_s * 16 + (row & 15);
    *(uint4*)&As[((wv * 4 + kc_s) * 64 + lane_t) * 4] = pk;
  }
  __syncthreads();

  const int w = tid >> 6;
  const int lane = tid & 63;
  bf16x8 a0 = *(bf16x8*)&As[((w * 4 + 0) * 64 + lane) * 4];
  bf16x8 a1 = *(bf16x8*)&As[((w * 4 + 1) * 64 + lane) * 4];
  bf16x8 a2 = *(bf16x8*)&As[((w * 4 + 2) * 64 + lane) * 4];
  bf16x8 a3 = *(bf16x8*)&As[((w * 4 + 3) * 64 + lane) * 4];
  f32x4 acc[8];
#pragma unroll
  for (int nt = 0; nt < 8; ++nt) acc[nt] = (f32x4){0.f, 0.f, 0.f, 0.f};
#pragma unroll
  for (int nt = 0; nt < 8; ++nt) {
    bf16x8 b0 = *(bf16x8*)&Bs[((nt * 4 + 0) * 64 + lane) * 4];
    bf16x8 b1 = *(bf16x8*)&Bs[((nt * 4 + 1) * 64 + lane) * 4];
    bf16x8 b2 = *(bf16x8*)&Bs[((nt * 4 + 2) * 64 + lane) * 4];
    bf16x8 b3 = *(bf16x8*)&Bs[((nt * 4 + 3) * 64 + lane) * 4];
    acc[nt] = __builtin_amdgcn_mfma_f32_16x16x32_bf16(a0, b0, acc[nt], 0, 0, 0);
    acc[nt] = __builtin_amdgcn_mfma_f32_16x16x32_bf16(a1, b1, acc[nt], 0, 0, 0);
    acc[nt] = __builtin_amdgcn_mfma_f32_16x16x32_bf16(a2, b2, acc[nt], 0, 0, 0);
    acc[nt] = __builtin_amdgcn_mfma_f32_16x16x32_bf16(a3, b3, acc[nt], 0, 0, 0);
  }
  const int colb = lane & 15;
  const int quad = lane >> 4;
#pragma unroll
  for (int nt = 0; nt < 8; ++nt) {
#pragma unroll
    for (int r = 0; r < 4; ++r) {
      int gr = R + w * 16 + quad * 4 + r;
      if (gr < nrows)
        OutH[(size_t)gr * 128 + nt * 16 + colb] = (u16)bf16_rtne(acc[nt][r]);
    }
  }
}

// ---------------- Aggregation: one block per 32-node bucket, LDS accumulators ----------------
// out[n] = dinv[n] * ( sum_e dinv[src]*h[src] + dinv[n]*h[n] ) + bias

__global__ __launch_bounds__(256) void k_agg(const uint* __restrict__ hb, const float* __restrict__ dinv,
                                             const int* __restrict__ bcur, const uint* __restrict__ stage,
                                             const float* __restrict__ bias,
                                             u16* __restrict__ outb, float* __restrict__ outf) {
  __shared__ float accx[2048];  // [dl][lane] : col 2*lane
  __shared__ float accy[2048];  // [dl][lane] : col 2*lane+1   (lane%32 banks -> 2-way, free)
  __shared__ float dns[BNODES];
  const int b = blockIdx.x;
  const int tid = threadIdx.x;
  const int w = tid >> 6;
  const int lane = tid & 63;
#pragma unroll
  for (int v = 0; v < 8; ++v) { accx[tid + v * 256] = 0.f; accy[tid + v * 256] = 0.f; }
  if (tid < BNODES) dns[tid] = dinv[b * BNODES + tid];
  __syncthreads();
  // self-loop terms: wave w exclusively owns dl = w, w+4, ... (no atomics needed)
  for (int dl = w; dl < BNODES; dl += 4) {
    int node = b * BNODES + dl;
    float dn = dns[dl];
    uint v = hb[(size_t)node * 64 + lane];
    accx[dl * 64 + lane] += dn * __uint_as_float(v << 16);
    accy[dl * 64 + lane] += dn * __uint_as_float(v & 0xffff0000u);
  }
  __syncthreads();
  // edges: each wave takes every 4th edge of each sub-list; one 256 B row gather per edge
  for (int s = 0; s < NSUB; ++s) {
    int idx = s * NBUCK + b;
    int n = bcur[idx]; if (n > SUBCAP) n = SUBCAP;
    int base = idx * SUBCAP;
    for (int i = w; i < n; i += 4) {
      uint u = stage[base + i];
      int src = (int)(u & 0x1FFFFu);
      int dl = (int)(u >> 17);
      float ds = dinv[src];
      uint v = hb[(size_t)src * 64 + lane];
      atomicAdd(&accx[dl * 64 + lane], ds * __uint_as_float(v << 16));
      atomicAdd(&accy[dl * 64 + lane], ds * __uint_as_float(v & 0xffff0000u));
    }
  }
  __syncthreads();
  // epilogue: dn*acc + bias -> bf16 (layer 1) or fp32 (layer 2)
#pragma unroll
  for (int q = 0; q < 16; ++q) {
    int idx2 = q * 256 + tid;
    int dl = idx2 >> 7;
    int c = idx2 & 127;
    float v = (c & 1) ? accy[dl * 64 + (c >> 1)] : accx[dl * 64 + (c >> 1)];
    float res = dns[dl] * v + bias[c];
    size_t node = (size_t)(b * BNODES + dl);
    if (outb) outb[node * 128 + c] = (u16)bf16_rtne(res);
    else      outf[node * 128 + c] = res;
  }
}

// ---------------- launch ----------------

extern "C" void kernel_launch(void* const* d_in, const int* in_sizes, int n_in,
                              void* d_out, int out_size, void* d_ws, size_t ws_size,
                              hipStream_t stream) {
  const float* x  = (const float*)d_in[0];
  const int*   ei = (const int*)d_in[1];   // int32: [0..E)=src, [E..2E)=dst
  const float* W1 = (const float*)d_in[2];
  const float* b1 = (const float*)d_in[3];
  const float* W2 = (const float*)d_in[4];
  const float* b2 = (const float*)d_in[5];
  float* out = (float*)d_out;

  char* p = (char*)d_ws;
  uint*  hb    = (uint*)p;  p += (size_t)N_NODES * 64 * sizeof(uint);            // 25.6 MB bf16 h table
  uint*  stage = (uint*)p;  p += (size_t)NBUCK * NSUB * SUBCAP * sizeof(uint);   // 12.8 MB
  uint*  wsw1  = (uint*)p;  p += 8192 * sizeof(uint);                            // 32 KB
  uint*  wsw2  = (uint*)p;  p += 8192 * sizeof(uint);                            // 32 KB
  int*   bcur  = (int*)p;   p += (size_t)NBUCK * NSUB * sizeof(int);             // 100 KB
  float* dinv  = (float*)p;                                                      // 400 KB

  // h1 (bf16, layer-1 activation) lives in d_out's scratch space: written by
  // agg1, consumed by gemm2, then agg2 overwrites all of d_out with the result.
  u16* h1b = (u16*)d_out;

  const int GG = (N_NODES + 63) / 64;  // 1563

  k_zero_cur<<<(NBUCK * NSUB + 255) / 256, 256, 0, stream>>>(bcur);
  k_bucket<<<(N_EDGES + 255) / 256, 256, 0, stream>>>(ei, bcur, stage);
  k_bcount<<<NBUCK, 256, 0, stream>>>(bcur, stage, dinv);
  k_prepw<<<dim3(8, 2), 256, 0, stream>>>(W1, W2, wsw1, wsw2);

  // layer 1
  k_gemm<<<GG, 256, 0, stream>>>(x, 1, wsw1, (u16*)hb, N_NODES);
  k_agg<<<NBUCK, 256, 0, stream>>>(hb, dinv, bcur, stage, b1, h1b, nullptr);
  // layer 2
  k_gemm<<<GG, 256, 0, stream>>>(h1b, 0, wsw2, (u16*)hb, N_NODES);
  k_agg<<<NBUCK, 256, 0, stream>>>(hb, dinv, bcur, stage, b2, nullptr, out);
}

// Round 8
// 383.335 us; speedup vs baseline: 6.2760x; 6.2760x over previous
//
#include <hip/hip_runtime.h>

#define N_NODES 100000
#define N_EDGES 1600000

#define BNODES 32
#define NBUCK 3125          // 100000 / 32 exactly
#define NSUB 8              // one sub-bucket per XCD (blockIdx & 7)
#define SUBCAP 128          // mean 64, ~8 sigma headroom

typedef unsigned int uint;
typedef unsigned short u16;
typedef __attribute__((ext_vector_type(8))) short bf16x8;  // 8 bf16 (4 VGPRs)
typedef __attribute__((ext_vector_type(4))) float f32x4;

__device__ __forceinline__ uint bf16_rtne(float f) {
  uint u = __float_as_uint(f);
  return (u + 0x7fffu + ((u >> 16) & 1u)) >> 16;
}

// ---------------- bucketed edge staging ----------------

__global__ __launch_bounds__(256) void k_zero_cur(int* __restrict__ bcur) {
  int i = blockIdx.x * 256 + threadIdx.x;
  if (i < NBUCK * NSUB) bcur[i] = 0;
}

// Append edges into dst-buckets; sub-bucket = blockIdx&7 keeps each stage
// region + cursor owned by ONE XCD's L2 (round-robin dispatch) -> ~1x write amp.
__global__ __launch_bounds__(256) void k_bucket(const int* __restrict__ ei, int* __restrict__ bcur,
                                                uint* __restrict__ stage) {
  int e = blockIdx.x * 256 + threadIdx.x;
  int sub = blockIdx.x & (NSUB - 1);
  if (e < N_EDGES) {
    int s = ei[e];
    int d = ei[N_EDGES + e];
    int b = d >> 5;
    int idx = sub * NBUCK + b;
    int pos = atomicAdd(&bcur[idx], 1);
    if (pos < SUBCAP)  // overflow guard (statistically unreachable)
      stage[idx * SUBCAP + pos] = (uint)s | ((uint)(d & 31) << 17);
  }
}

// per-bucket degree count (LDS only) -> dinv + bucket total (for the small scan)
__global__ __launch_bounds__(256) void k_bcount(const int* __restrict__ bcur, const uint* __restrict__ stage,
                                                float* __restrict__ dinv, int* __restrict__ btot) {
  __shared__ int cnt[BNODES];
  int b = blockIdx.x, t = threadIdx.x;
  if (t < BNODES) cnt[t] = 0;
  __syncthreads();
  int tot = 0;
  for (int s = 0; s < NSUB; ++s) {
    int idx = s * NBUCK + b;
    int n = bcur[idx]; if (n > SUBCAP) n = SUBCAP;
    tot += n;
    int base = idx * SUBCAP;
    for (int i = t; i < n; i += 256) atomicAdd(&cnt[stage[base + i] >> 17], 1);
  }
  __syncthreads();
  if (t < BNODES) dinv[b * BNODES + t] = rsqrtf((float)(cnt[t] + 1));  // +1 self-loop
  if (t == 0) btot[b] = tot;
}

// single-block exclusive scan over 3125 bucket totals -> bucketbase
__global__ __launch_bounds__(256) void k_bscan(const int* __restrict__ btot, int* __restrict__ bbase,
                                               int* __restrict__ rowptr) {
  __shared__ int sd[256];
  const int t = threadIdx.x;
  const int per = (NBUCK + 255) / 256;  // 13
  int v[13];
  int s = 0;
#pragma unroll
  for (int j = 0; j < per; ++j) {
    int i = t * per + j;
    v[j] = (i < NBUCK) ? btot[i] : 0;
    s += v[j];
  }
  sd[t] = s;
  __syncthreads();
  for (int off = 1; off < 256; off <<= 1) {
    int a = (t >= off) ? sd[t - off] : 0;
    __syncthreads();
    sd[t] += a;
    __syncthreads();
  }
  int run = sd[t] - s;  // exclusive prefix of this thread's chunk
#pragma unroll
  for (int j = 0; j < per; ++j) {
    int i = t * per + j;
    if (i < NBUCK) { bbase[i] = run; run += v[j]; }
  }
  if (t == 255) rowptr[N_NODES] = run;
}

// fused: recount -> 32-wide scan -> rowptr -> scatter (src,dinv[src]) into CSR range
__global__ __launch_bounds__(256) void k_scatter(const int* __restrict__ bcur, const uint* __restrict__ stage,
                                                 const int* __restrict__ bbase, const float* __restrict__ dinv,
                                                 int* __restrict__ rowptr, int2* __restrict__ ep) {
  __shared__ int cnt[BNODES];
  __shared__ int cur[BNODES];
  int b = blockIdx.x, t = threadIdx.x;
  if (t < BNODES) cnt[t] = 0;
  __syncthreads();
  for (int s = 0; s < NSUB; ++s) {
    int idx = s * NBUCK + b;
    int n = bcur[idx]; if (n > SUBCAP) n = SUBCAP;
    int base = idx * SUBCAP;
    for (int i = t; i < n; i += 256) atomicAdd(&cnt[stage[base + i] >> 17], 1);
  }
  __syncthreads();
  if (t < BNODES) {
    int pre = 0;
#pragma unroll
    for (int j = 0; j < BNODES; ++j) pre += (j < t) ? cnt[j] : 0;
    int c = bbase[b] + pre;
    cur[t] = c;
    rowptr[b * BNODES + t] = c;
  }
  __syncthreads();
  for (int s = 0; s < NSUB; ++s) {
    int idx = s * NBUCK + b;
    int n = bcur[idx]; if (n > SUBCAP) n = SUBCAP;
    int base = idx * SUBCAP;
    for (int i = t; i < n; i += 256) {
      uint u = stage[base + i];
      int src = (int)(u & 0x1FFFFu);
      int dl = (int)(u >> 17);
      int pos = atomicAdd(&cur[dl], 1);
      int2 pr;
      pr.x = src;
      pr.y = __float_as_int(dinv[src]);
      ep[pos] = pr;
    }
  }
}

// ---------------- W pre-swizzle to MFMA B-fragment order ----------------

__global__ __launch_bounds__(256) void k_prepw(const float* __restrict__ W1, const float* __restrict__ W2,
                                               uint* __restrict__ S1, uint* __restrict__ S2) {
  int u = blockIdx.x * 256 + threadIdx.x;  // 0..2047
  const float* W = blockIdx.y ? W2 : W1;
  uint* S = blockIdx.y ? S2 : S1;
  int lane = u & 63;
  int kcnt = u >> 6;
  int kc = kcnt & 3;
  int nt = kcnt >> 2;
  int n = nt * 16 + (lane & 15);
  int k0 = kc * 32 + (lane >> 4) * 8;
  float f[8];
#pragma unroll
  for (int j = 0; j < 8; ++j) f[j] = W[(size_t)(k0 + j) * 128 + n];
  uint4 pk;
  pk.x = bf16_rtne(f[0]) | (bf16_rtne(f[1]) << 16);
  pk.y = bf16_rtne(f[2]) | (bf16_rtne(f[3]) << 16);
  pk.z = bf16_rtne(f[4]) | (bf16_rtne(f[5]) << 16);
  pk.w = bf16_rtne(f[6]) | (bf16_rtne(f[7]) << 16);
  ((uint4*)S)[u] = pk;
}

// ---------------- MFMA GEMM: OutH[nrows,128](bf16) = A[nrows,128] @ W ----------------
// 64 rows/block, 4 waves, wave w owns rows w*16..w*16+15, sweeps 8 n-tiles.

__global__ __launch_bounds__(256) void k_gemm(const void* __restrict__ Ain, int a_f32,
                                              const uint* __restrict__ Wsw,
                                              u16* __restrict__ OutH, int nrows) {
  __shared__ uint As[4096];   // 16 KB A fragments
  __shared__ uint Bs[8192];   // 32 KB B fragments
  const int tid = threadIdx.x;
  const int R = blockIdx.x * 64;
  {
    const uint4* src = (const uint4*)Wsw;
    uint4* dst = (uint4*)Bs;
#pragma unroll
    for (int v = 0; v < 8; ++v) dst[tid + v * 256] = src[tid + v * 256];
  }
  const int unit = tid & 15;      // k8-slice 0..15
  const int kc_s = unit >> 2;
  const int quad_s = unit & 3;
#pragma unroll
  for (int pass = 0; pass < 4; ++pass) {
    int row = pass * 16 + (tid >> 4);
    int gr = R + row;
    if (gr >= nrows) gr = nrows - 1;
    uint4 pk;
    if (a_f32) {
      const float* srcr = (const float*)Ain + (size_t)gr * 128 + unit * 8;
      float4 f0 = ((const float4*)srcr)[0];
      float4 f1 = ((const float4*)srcr)[1];
      pk.x = bf16_rtne(f0.x) | (bf16_rtne(f0.y) << 16);
      pk.y = bf16_rtne(f0.z) | (bf16_rtne(f0.w) << 16);
      pk.z = bf16_rtne(f1.x) | (bf16_rtne(f1.y) << 16);
      pk.w = bf16_rtne(f1.z) | (bf16_rtne(f1.w) << 16);
    } else {
      pk = ((const uint4*)((const uint*)Ain + (size_t)gr * 64))[unit];
    }
    int lane_t = quad_s * 16 + (row & 15);
    *(uint4*)&As[((pass * 4 + kc_s) * 64 + lane_t) * 4] = pk;
  }
  __syncthreads();

  const int w = tid >> 6;
  const int lane = tid & 63;
  bf16x8 a0 = *(bf16x8*)&As[((w * 4 + 0) * 64 + lane) * 4];
  bf16x8 a1 = *(bf16x8*)&As[((w * 4 + 1) * 64 + lane) * 4];
  bf16x8 a2 = *(bf16x8*)&As[((w * 4 + 2) * 64 + lane) * 4];
  bf16x8 a3 = *(bf16x8*)&As[((w * 4 + 3) * 64 + lane) * 4];
  f32x4 acc[8];
#pragma unroll
  for (int nt = 0; nt < 8; ++nt) acc[nt] = (f32x4){0.f, 0.f, 0.f, 0.f};
#pragma unroll
  for (int nt = 0; nt < 8; ++nt) {
    bf16x8 b0 = *(bf16x8*)&Bs[((nt * 4 + 0) * 64 + lane) * 4];
    bf16x8 b1 = *(bf16x8*)&Bs[((nt * 4 + 1) * 64 + lane) * 4];
    bf16x8 b2 = *(bf16x8*)&Bs[((nt * 4 + 2) * 64 + lane) * 4];
    bf16x8 b3 = *(bf16x8*)&Bs[((nt * 4 + 3) * 64 + lane) * 4];
    acc[nt] = __builtin_amdgcn_mfma_f32_16x16x32_bf16(a0, b0, acc[nt], 0, 0, 0);
    acc[nt] = __builtin_amdgcn_mfma_f32_16x16x32_bf16(a1, b1, acc[nt], 0, 0, 0);
    acc[nt] = __builtin_amdgcn_mfma_f32_16x16x32_bf16(a2, b2, acc[nt], 0, 0, 0);
    acc[nt] = __builtin_amdgcn_mfma_f32_16x16x32_bf16(a3, b3, acc[nt], 0, 0, 0);
  }
  const int colb = lane & 15;
  const int quad = lane >> 4;
#pragma unroll
  for (int nt = 0; nt < 8; ++nt) {
#pragma unroll
    for (int r = 0; r < 4; ++r) {
      int gr = R + w * 16 + quad * 4 + r;
      if (gr < nrows)
        OutH[(size_t)gr * 128 + nt * 16 + colb] = (u16)bf16_rtne(acc[nt][r]);
    }
  }
}

// ---------------- Aggregation: one wave per node, register accum (R5-proven) ----------------

__device__ __forceinline__ void bacc(float& ax, float& ay, uint v, float w) {
  ax += w * __uint_as_float(v << 16);
  ay += w * __uint_as_float(v & 0xffff0000u);
}

__global__ __launch_bounds__(256) void k_agg(const uint* __restrict__ hb, const float* __restrict__ dinv,
                                             const int* __restrict__ rowptr, const int2* __restrict__ ep,
                                             const float* __restrict__ bias,
                                             u16* __restrict__ outb, float* __restrict__ outf) {
  int wid = threadIdx.x >> 6;
  int lane = threadIdx.x & 63;
  int node = blockIdx.x * 4 + wid;
  if (node >= N_NODES) return;
  int beg = rowptr[node];
  int end = rowptr[node + 1];
  float dn = dinv[node];
  uint selfv = hb[(size_t)node * 64 + lane];
  float ax = 0.f, ay = 0.f;
  bacc(ax, ay, selfv, dn);

  int e = beg;
  for (; e + 4 <= end; e += 4) {
    int2 p0 = ep[e];
    int2 p1 = ep[e + 1];
    int2 p2 = ep[e + 2];
    int2 p3 = ep[e + 3];
    uint v0 = hb[(size_t)p0.x * 64 + lane];
    uint v1 = hb[(size_t)p1.x * 64 + lane];
    uint v2 = hb[(size_t)p2.x * 64 + lane];
    uint v3 = hb[(size_t)p3.x * 64 + lane];
    bacc(ax, ay, v0, __int_as_float(p0.y));
    bacc(ax, ay, v1, __int_as_float(p1.y));
    bacc(ax, ay, v2, __int_as_float(p2.y));
    bacc(ax, ay, v3, __int_as_float(p3.y));
  }
  for (; e < end; ++e) {
    int2 p = ep[e];
    uint v = hb[(size_t)p.x * 64 + lane];
    bacc(ax, ay, v, __int_as_float(p.y));
  }

  int c = lane * 2;
  float rx = dn * ax + bias[c];
  float ry = dn * ay + bias[c + 1];
  if (outb) {
    uint pk = bf16_rtne(rx) | (bf16_rtne(ry) << 16);
    *(uint*)(outb + (size_t)node * 128 + c) = pk;
  } else {
    float2 o; o.x = rx; o.y = ry;
    *(float2*)(outf + (size_t)node * 128 + c) = o;
  }
}

// ---------------- launch ----------------

extern "C" void kernel_launch(void* const* d_in, const int* in_sizes, int n_in,
                              void* d_out, int out_size, void* d_ws, size_t ws_size,
                              hipStream_t stream) {
  const float* x  = (const float*)d_in[0];
  const int*   ei = (const int*)d_in[1];   // int32: [0..E)=src, [E..2E)=dst
  const float* W1 = (const float*)d_in[2];
  const float* b1 = (const float*)d_in[3];
  const float* W2 = (const float*)d_in[4];
  const float* b2 = (const float*)d_in[5];
  float* out = (float*)d_out;

  char* p = (char*)d_ws;
  uint*  hb     = (uint*)p;  p += (size_t)N_NODES * 64 * sizeof(uint);            // 25.6 MB bf16 h table
  int2*  ep     = (int2*)p;  p += (size_t)N_EDGES * sizeof(int2);                 // 12.8 MB
  uint*  stage  = (uint*)p;  p += (size_t)NBUCK * NSUB * SUBCAP * sizeof(uint);   // 12.8 MB
  uint*  wsw1   = (uint*)p;  p += 8192 * sizeof(uint);                            // 32 KB
  uint*  wsw2   = (uint*)p;  p += 8192 * sizeof(uint);                            // 32 KB
  int*   bcur   = (int*)p;   p += (size_t)NBUCK * NSUB * sizeof(int);             // 100 KB
  float* dinv   = (float*)p; p += (size_t)N_NODES * sizeof(float);                // 400 KB
  int*   rowptr = (int*)p;   p += (size_t)(N_NODES + 1) * sizeof(int);            // 400 KB
  int*   btot   = (int*)p;   p += (size_t)NBUCK * sizeof(int);
  int*   bbase  = (int*)p;

  // h1 (bf16 layer-1 activation) lives in d_out scratch: written by agg1,
  // consumed by gemm2, then agg2 overwrites all of d_out.
  u16* h1b = (u16*)d_out;

  const int GG = (N_NODES + 63) / 64;  // 1563

  k_zero_cur<<<(NBUCK * NSUB + 255) / 256, 256, 0, stream>>>(bcur);
  k_bucket<<<(N_EDGES + 255) / 256, 256, 0, stream>>>(ei, bcur, stage);
  k_bcount<<<NBUCK, 256, 0, stream>>>(bcur, stage, dinv, btot);
  k_bscan<<<1, 256, 0, stream>>>(btot, bbase, rowptr);
  k_scatter<<<NBUCK, 256, 0, stream>>>(bcur, stage, bbase, dinv, rowptr, ep);
  k_prepw<<<dim3(8, 2), 256, 0, stream>>>(W1, W2, wsw1, wsw2);

  // layer 1
  k_gemm<<<GG, 256, 0, stream>>>(x, 1, wsw1, (u16*)hb, N_NODES);
  k_agg<<<(N_NODES + 3) / 4, 256, 0, stream>>>(hb, dinv, rowptr, ep, b1, h1b, nullptr);
  // layer 2
  k_gemm<<<GG, 256, 0, stream>>>(h1b, 0, wsw2, (u16*)hb, N_NODES);
  k_agg<<<(N_NODES + 3) / 4, 256, 0, stream>>>(hb, dinv, rowptr, ep, b2, nullptr, out);
}